// Round 1
// baseline (21701.376 us; speedup 1.0000x reference)
//
#include <hip/hip_runtime.h>
#include <cstdint>
#include <cstddef>

#define NB 64
#define NH 512
#define NA 256
#define NV 10000
#define NT 151
#define NL 49

// ---------------- batched 32x32 tiled transpose: out[c*R + r] = in[r*C + c] ----------------
__global__ __launch_bounds__(256) void k_transpose(const float* __restrict__ in,
    float* __restrict__ out, int R, int C, long long inBS, long long outBS) {
  __shared__ float tl[32][33];
  const int b = blockIdx.z;
  in  += (size_t)b * (size_t)inBS;
  out += (size_t)b * (size_t)outBS;
  const int c0 = blockIdx.x * 32, r0 = blockIdx.y * 32;
  const int x = threadIdx.x & 31, y = threadIdx.x >> 5;
#pragma unroll
  for (int i = 0; i < 4; ++i) {
    int r = r0 + y + i * 8;
    if (r < R && c0 + x < C) tl[y + i * 8][x] = in[(size_t)r * C + c0 + x];
  }
  __syncthreads();
#pragma unroll
  for (int i = 0; i < 4; ++i) {
    int c = c0 + y + i * 8;
    if (c < C && r0 + x < R) out[(size_t)c * R + r0 + x] = tl[x][y + i * 8];
  }
}

// ---------------- generic tiled GEMM: C[MxN] = A[MxK] @ B[KxN] + bias ----------------
__global__ __launch_bounds__(256) void k_gemm_bias(const float* __restrict__ A, int lda,
    const float* __restrict__ B, int ldb, float* __restrict__ C, int ldc,
    int M, int N, int K, const float* __restrict__ bias) {
  __shared__ float As[16][65];   // [k][m], padded stride 65 to avoid store conflicts
  __shared__ float Bs[16][64];   // [k][n]
  const int tid = threadIdx.x;
  const int tx = tid & 15, ty = tid >> 4;
  const int m0 = blockIdx.y * 64, n0 = blockIdx.x * 64;
  float acc[4][4] = {};
  for (int k0 = 0; k0 < K; k0 += 16) {
#pragma unroll
    for (int i = 0; i < 4; ++i) {
      int idx = i * 256 + tid;
      int r = idx >> 4, kk = idx & 15;
      int m = m0 + r;
      As[kk][r] = (m < M) ? A[(size_t)m * lda + k0 + kk] : 0.f;
    }
#pragma unroll
    for (int i = 0; i < 4; ++i) {
      int idx = i * 256 + tid;
      int kk = idx >> 6, c = idx & 63;
      int n = n0 + c;
      Bs[kk][c] = (n < N) ? B[(size_t)(k0 + kk) * ldb + n] : 0.f;
    }
    __syncthreads();
#pragma unroll
    for (int kk = 0; kk < 16; ++kk) {
      float a[4], bv[4];
#pragma unroll
      for (int i = 0; i < 4; ++i) a[i] = As[kk][ty * 4 + i];
#pragma unroll
      for (int j = 0; j < 4; ++j) bv[j] = Bs[kk][tx * 4 + j];
#pragma unroll
      for (int i = 0; i < 4; ++i)
#pragma unroll
        for (int j = 0; j < 4; ++j) acc[i][j] = fmaf(a[i], bv[j], acc[i][j]);
    }
    __syncthreads();
  }
#pragma unroll
  for (int i = 0; i < 4; ++i) {
    int m = m0 + ty * 4 + i;
    if (m >= M) continue;
#pragma unroll
    for (int j = 0; j < 4; ++j) {
      int n = n0 + tx * 4 + j;
      if (n >= N) continue;
      C[(size_t)m * ldc + n] = acc[i][j] + (bias ? bias[n] : 0.f);
    }
  }
}

// ---------------- h0 = mean over L of enc ----------------
__global__ __launch_bounds__(256) void k_h0(const float* __restrict__ enc, float* __restrict__ h0) {
  int b = blockIdx.x;
  int j = blockIdx.y * 256 + threadIdx.x;
  float s = 0.f;
  for (int l = 0; l < NL; ++l) s += enc[((size_t)b * NL + l) * NH + j];
  h0[b * NH + j] = s / 49.0f;
}

// ---------------- inp0 = embed[start], seq[:,0,:] = inp0 ----------------
__global__ __launch_bounds__(256) void k_prep0(const float* __restrict__ embed,
    const int* __restrict__ start, float* __restrict__ inp0, float* __restrict__ seq) {
  int idx = blockIdx.x * 256 + threadIdx.x;   // 0..32767
  int b = idx >> 9, j = idx & 511;
  float v = embed[(size_t)start[0] * NH + j];
  inp0[idx] = v;
  seq[((size_t)b * NT) * NH + j] = v;
}

// ---------------- step stage 1: att2 = h@W_dec + b_dec ; hWc1 = inp@W_comb[0:512] ----------------
__global__ __launch_bounds__(256) void k_step1(const float* __restrict__ h,
    const float* __restrict__ inp, const float* __restrict__ W_dec,
    const float* __restrict__ b_dec, const float* __restrict__ W_comb,
    float* __restrict__ att2, float* __restrict__ hWc1) {
  const int b = blockIdx.y;
  const int c = blockIdx.x * 256 + threadIdx.x;   // 0..767, wave-uniform segments
  if (c < NA) {
    float acc = b_dec[c];
    const float* hb = h + b * NH;
    for (int k = 0; k < NH; ++k) acc = fmaf(hb[k], W_dec[(size_t)k * NA + c], acc);
    att2[b * NA + c] = acc;
  } else {
    int j = c - NA;
    float acc = 0.f;
    const float* ib = inp + b * NH;
    for (int k = 0; k < NH; ++k) acc = fmaf(ib[k], W_comb[(size_t)k * NH + j], acc);
    hWc1[b * NH + j] = acc;
  }
}

// ---------------- step stage 2 (per-batch): e, softmax, comb ----------------
__global__ __launch_bounds__(256) void k_step2(const float* __restrict__ att1,
    const float* __restrict__ att2, const float* __restrict__ encWc2,
    const float* __restrict__ hWc1, const float* __restrict__ b_comb,
    const float* __restrict__ W_full, const float* __restrict__ b_full,
    float* __restrict__ comb) {
  const int b = blockIdx.x;
  const int tid = threadIdx.x;
  const int lane = tid & 63, wave = tid >> 6;
  __shared__ float a2[NA];
  __shared__ float sE[64];
  a2[tid] = att2[b * NA + tid];
  __syncthreads();
  // e[l] = W_full . tanh(att1[b,l,:] + att2[b,:]) + b_full
  for (int l = wave; l < NL; l += 4) {
    const float* row = att1 + ((size_t)b * NL + l) * NA;
    float s = 0.f;
    for (int a = lane; a < NA; a += 64)
      s = fmaf(W_full[a], tanhf(row[a] + a2[a]), s);
#pragma unroll
    for (int off = 32; off > 0; off >>= 1) s += __shfl_down(s, off);
    if (lane == 0) sE[l] = s + b_full[0];
  }
  __syncthreads();
  // softmax over L=49 -> alpha in sE
  if (wave == 0) {
    float v = (lane < NL) ? sE[lane] : -INFINITY;
    float m = v;
#pragma unroll
    for (int off = 32; off > 0; off >>= 1) m = fmaxf(m, __shfl_xor(m, off));
    float e = (lane < NL) ? expf(v - m) : 0.f;
    float sum = e;
#pragma unroll
    for (int off = 32; off > 0; off >>= 1) sum += __shfl_xor(sum, off);
    if (lane < NL) sE[lane] = e / sum;
  }
  __syncthreads();
  // comb[j] = tanh(hWc1[j] + sum_l alpha_l * encWc2[b,l,j] + b_comb[j])
  for (int j = tid; j < NH; j += 256) {
    float acc = hWc1[b * NH + j] + b_comb[j];
    const float* ew = encWc2 + (size_t)b * NL * NH + j;
    for (int l = 0; l < NL; ++l) acc = fmaf(sE[l], ew[(size_t)l * NH], acc);
    comb[b * NH + j] = tanhf(acc);
  }
}

// ---------------- step stage 3: gi = comb@W_ih^T, gh = h@W_hh^T, GRU combine ----------------
__global__ __launch_bounds__(256) void k_step3(const float* __restrict__ comb,
    const float* __restrict__ h, const float* __restrict__ WihT,
    const float* __restrict__ WhhT, const float* __restrict__ b_ih,
    const float* __restrict__ b_hh, float* __restrict__ hout,
    float* __restrict__ seq, int t) {
  const int b = blockIdx.y;
  const int j = blockIdx.x * 256 + threadIdx.x;   // 0..511
  const float* cb = comb + b * NH;
  const float* hb = h + b * NH;
  float gr = 0.f, gz = 0.f, gn = 0.f, hr = 0.f, hz = 0.f, hn = 0.f;
  for (int k = 0; k < NH; ++k) {
    float c = cb[k], hh = hb[k];
    const float* wi = WihT + (size_t)k * (3 * NH);
    const float* wh = WhhT + (size_t)k * (3 * NH);
    gr = fmaf(c, wi[j], gr);
    gz = fmaf(c, wi[NH + j], gz);
    gn = fmaf(c, wi[2 * NH + j], gn);
    hr = fmaf(hh, wh[j], hr);
    hz = fmaf(hh, wh[NH + j], hz);
    hn = fmaf(hh, wh[2 * NH + j], hn);
  }
  float r = 1.f / (1.f + expf(-(gr + b_ih[j] + hr + b_hh[j])));
  float z = 1.f / (1.f + expf(-(gz + b_ih[NH + j] + hz + b_hh[NH + j])));
  float n = tanhf(gn + b_ih[2 * NH + j] + r * (hn + b_hh[2 * NH + j]));
  float hv = (1.f - z) * n + z * hb[j];
  hout[b * NH + j] = hv;
  seq[((size_t)b * NT + t) * NH + j] = hv;
}

// ---------------- projection: out[b,v,t] = seq[b,t,:] . W_proj[:,v] + b_proj[v], fused argmax ----------------
__global__ __launch_bounds__(256) void k_proj(const float* __restrict__ Wp,
    const float* __restrict__ seq, const float* __restrict__ bias,
    float* __restrict__ out, unsigned long long* __restrict__ packed) {
  __shared__ float As[32][128];   // [k][v]
  __shared__ float Bs[32][81];    // [k][t], stride 81 -> conflict-free transpose store
  const int tid = threadIdx.x;
  const int tx = tid & 15, ty = tid >> 4;
  const int v0 = blockIdx.x * 128;
  const int t0 = blockIdx.y * 80;
  const int b = blockIdx.z;
  float acc[8][5] = {};
  for (int k0 = 0; k0 < NH; k0 += 32) {
#pragma unroll
    for (int i = 0; i < 16; ++i) {
      int idx = i * 256 + tid;
      int kk = idx >> 7, v = idx & 127;
      int gv = v0 + v;
      As[kk][v] = (gv < NV) ? Wp[(size_t)(k0 + kk) * NV + gv] : 0.f;
    }
#pragma unroll
    for (int i = 0; i < 10; ++i) {
      int idx = i * 256 + tid;
      int t = idx >> 5, kk = idx & 31;
      int gt = t0 + t;
      Bs[kk][t] = (gt < NT) ? seq[((size_t)b * NT + gt) * NH + k0 + kk] : 0.f;
    }
    __syncthreads();
#pragma unroll
    for (int kk = 0; kk < 32; ++kk) {
      const float4 a0 = *(const float4*)&As[kk][ty * 8];
      const float4 a1 = *(const float4*)&As[kk][ty * 8 + 4];
      float av[8] = {a0.x, a0.y, a0.z, a0.w, a1.x, a1.y, a1.z, a1.w};
      float bv[5];
#pragma unroll
      for (int j = 0; j < 5; ++j) bv[j] = Bs[kk][tx * 5 + j];
#pragma unroll
      for (int i = 0; i < 8; ++i)
#pragma unroll
        for (int j = 0; j < 5; ++j) acc[i][j] = fmaf(av[i], bv[j], acc[i][j]);
    }
    __syncthreads();
  }
  // epilogue: bias add, transposed store (t-contiguous), tile-local argmax
  float best[5] = {-INFINITY, -INFINITY, -INFINITY, -INFINITY, -INFINITY};
  int bestv[5] = {0, 0, 0, 0, 0};
#pragma unroll
  for (int i = 0; i < 8; ++i) {
    int gv = v0 + ty * 8 + i;
    if (gv >= NV) continue;
    float bi = bias[gv];
#pragma unroll
    for (int j = 0; j < 5; ++j) {
      int gt = t0 + tx * 5 + j;
      if (gt >= NT) continue;
      float val = acc[i][j] + bi;
      out[((size_t)b * NV + gv) * NT + gt] = val;
      if (val > best[j]) { best[j] = val; bestv[j] = gv; }  // strict > keeps first (smallest v)
    }
  }
  __syncthreads();
  float* rb = &As[0][0];       // 16 x 80 floats (reuse LDS)
  int* ri = (int*)&Bs[0][0];   // 16 x 80 ints
#pragma unroll
  for (int j = 0; j < 5; ++j) {
    rb[ty * 80 + tx * 5 + j] = best[j];
    ri[ty * 80 + tx * 5 + j] = bestv[j];
  }
  __syncthreads();
  if (ty == 0) {
    for (int j = 0; j < 5; ++j) {
      int gt = t0 + tx * 5 + j;
      if (gt >= NT) continue;
      float bb = -INFINITY; int bv_ = 0;
      for (int g = 0; g < 16; ++g) {      // ascending g = ascending v -> first-max semantics
        float v = rb[g * 80 + tx * 5 + j];
        if (v > bb) { bb = v; bv_ = ri[g * 80 + tx * 5 + j]; }
      }
      unsigned int u = __float_as_uint(bb);
      u = (u & 0x80000000u) ? ~u : (u | 0x80000000u);   // order-preserving float->uint
      unsigned long long p = ((unsigned long long)u << 32) | (unsigned int)(NV - 1 - bv_);
      atomicMax(&packed[b * NT + gt], p);
    }
  }
}

__global__ __launch_bounds__(256) void k_tokens(const unsigned long long* __restrict__ packed,
    float* __restrict__ tok) {
  int i = blockIdx.x * 256 + threadIdx.x;
  if (i < NB * NT) {
    unsigned int low = (unsigned int)(packed[i] & 0xFFFFFFFFull);
    tok[i] = (float)(NV - 1 - (int)low);
  }
}

extern "C" void kernel_launch(void* const* d_in, const int* in_sizes, int n_in,
                              void* d_out, int out_size, void* d_ws, size_t ws_size,
                              hipStream_t stream) {
  const float* enc_feat = (const float*)d_in[0];
  const float* W_fp   = (const float*)d_in[1];
  const float* b_fp   = (const float*)d_in[2];
  const float* W_enc  = (const float*)d_in[3];
  const float* b_enc  = (const float*)d_in[4];
  const float* W_dec  = (const float*)d_in[5];
  const float* b_dec  = (const float*)d_in[6];
  const float* W_full = (const float*)d_in[7];
  const float* b_full = (const float*)d_in[8];
  const float* W_comb = (const float*)d_in[9];
  const float* b_comb = (const float*)d_in[10];
  const float* embed  = (const float*)d_in[11];
  const float* W_ih   = (const float*)d_in[12];
  const float* b_ih   = (const float*)d_in[13];
  const float* W_hh   = (const float*)d_in[14];
  const float* b_hh   = (const float*)d_in[15];
  const float* W_proj = (const float*)d_in[16];
  const float* b_proj = (const float*)d_in[17];
  const int*   start  = (const int*)d_in[18];

  float* wsf = (float*)d_ws;
  size_t o = 0;
  float* encT   = wsf + o; o += (size_t)NB * NL * NH;     // 1,605,632
  float* enc    = wsf + o; o += (size_t)NB * NL * NH;
  float* att1   = wsf + o; o += (size_t)NB * NL * NA;
  float* encWc2 = wsf + o; o += (size_t)NB * NL * NH;
  float* WihT   = wsf + o; o += (size_t)NH * 3 * NH;
  float* WhhT   = wsf + o; o += (size_t)NH * 3 * NH;
  float* seq    = wsf + o; o += (size_t)NB * NT * NH;
  float* hb0    = wsf + o; o += NB * NH;
  float* hb1    = wsf + o; o += NB * NH;
  float* inp0   = wsf + o; o += NB * NH;
  float* att2   = wsf + o; o += NB * NA;
  float* hWc1   = wsf + o; o += NB * NH;
  float* comb   = wsf + o; o += NB * NH;
  unsigned long long* packed = (unsigned long long*)(wsf + o); o += 2 * NB * NT;
  // total ~47 MiB of d_ws

  // ---- precompute ----
  k_transpose<<<dim3(2, 16, 64), 256, 0, stream>>>(enc_feat, encT, NH, NL,
      (long long)NH * NL, (long long)NH * NL);
  k_gemm_bias<<<dim3(8, 49), 256, 0, stream>>>(encT, NH, W_fp, NH, enc, NH,
      NB * NL, NH, NH, b_fp);
  k_h0<<<dim3(64, 2), 256, 0, stream>>>(enc, hb0);
  k_prep0<<<128, 256, 0, stream>>>(embed, start, inp0, seq);
  k_transpose<<<dim3(16, 48, 1), 256, 0, stream>>>(W_ih, WihT, 3 * NH, NH, 0, 0);
  k_transpose<<<dim3(16, 48, 1), 256, 0, stream>>>(W_hh, WhhT, 3 * NH, NH, 0, 0);
  k_gemm_bias<<<dim3(4, 49), 256, 0, stream>>>(enc, NH, W_enc, NA, att1, NA,
      NB * NL, NA, NH, b_enc);
  k_gemm_bias<<<dim3(8, 49), 256, 0, stream>>>(enc, NH, W_comb + (size_t)NH * NH, NH,
      encWc2, NH, NB * NL, NH, NH, nullptr);

  // ---- sequential recurrence: 150 steps x 3 kernels ----
  float* hprev = hb0;
  float* hnext = hb1;
  for (int t = 1; t < NT; ++t) {
    const float* inp = (t == 1) ? inp0 : hprev;
    k_step1<<<dim3(3, 64), 256, 0, stream>>>(hprev, inp, W_dec, b_dec, W_comb, att2, hWc1);
    k_step2<<<64, 256, 0, stream>>>(att1, att2, encWc2, hWc1, b_comb, W_full, b_full, comb);
    k_step3<<<dim3(2, 64), 256, 0, stream>>>(comb, hprev, WihT, WhhT, b_ih, b_hh,
        hnext, seq, t);
    float* tmp = hprev; hprev = hnext; hnext = tmp;
  }

  // ---- projection + argmax ----
  hipMemsetAsync(packed, 0, sizeof(unsigned long long) * NB * NT, stream);
  float* outf = (float*)d_out;
  k_proj<<<dim3(79, 2, 64), 256, 0, stream>>>(W_proj, seq, b_proj, outf, packed);
  k_tokens<<<38, 256, 0, stream>>>(packed, outf + (size_t)NB * NV * NT);
}

// Round 2
// 13524.179 us; speedup vs baseline: 1.6046x; 1.6046x over previous
//
#include <hip/hip_runtime.h>
#include <cstdint>
#include <cstddef>

#define NB 64
#define NH 512
#define NA 256
#define NV 10000
#define NT 151
#define NL 49

// ---------------- batched 32x32 tiled transpose: out[c*R + r] = in[r*C + c] ----------------
__global__ __launch_bounds__(256) void k_transpose(const float* __restrict__ in,
    float* __restrict__ out, int R, int C, long long inBS, long long outBS) {
  __shared__ float tl[32][33];
  const int b = blockIdx.z;
  in  += (size_t)b * (size_t)inBS;
  out += (size_t)b * (size_t)outBS;
  const int c0 = blockIdx.x * 32, r0 = blockIdx.y * 32;
  const int x = threadIdx.x & 31, y = threadIdx.x >> 5;
#pragma unroll
  for (int i = 0; i < 4; ++i) {
    int r = r0 + y + i * 8;
    if (r < R && c0 + x < C) tl[y + i * 8][x] = in[(size_t)r * C + c0 + x];
  }
  __syncthreads();
#pragma unroll
  for (int i = 0; i < 4; ++i) {
    int c = c0 + y + i * 8;
    if (c < C && r0 + x < R) out[(size_t)c * R + r0 + x] = tl[x][y + i * 8];
  }
}

// ---------------- generic tiled GEMM: C[MxN] = A[MxK] @ B[KxN] + bias ----------------
__global__ __launch_bounds__(256) void k_gemm_bias(const float* __restrict__ A, int lda,
    const float* __restrict__ B, int ldb, float* __restrict__ C, int ldc,
    int M, int N, int K, const float* __restrict__ bias) {
  __shared__ float As[16][65];
  __shared__ float Bs[16][64];
  const int tid = threadIdx.x;
  const int tx = tid & 15, ty = tid >> 4;
  const int m0 = blockIdx.y * 64, n0 = blockIdx.x * 64;
  float acc[4][4] = {};
  for (int k0 = 0; k0 < K; k0 += 16) {
#pragma unroll
    for (int i = 0; i < 4; ++i) {
      int idx = i * 256 + tid;
      int r = idx >> 4, kk = idx & 15;
      int m = m0 + r;
      As[kk][r] = (m < M) ? A[(size_t)m * lda + k0 + kk] : 0.f;
    }
#pragma unroll
    for (int i = 0; i < 4; ++i) {
      int idx = i * 256 + tid;
      int kk = idx >> 6, c = idx & 63;
      int n = n0 + c;
      Bs[kk][c] = (n < N) ? B[(size_t)(k0 + kk) * ldb + n] : 0.f;
    }
    __syncthreads();
#pragma unroll
    for (int kk = 0; kk < 16; ++kk) {
      float a[4], bv[4];
#pragma unroll
      for (int i = 0; i < 4; ++i) a[i] = As[kk][ty * 4 + i];
#pragma unroll
      for (int j = 0; j < 4; ++j) bv[j] = Bs[kk][tx * 4 + j];
#pragma unroll
      for (int i = 0; i < 4; ++i)
#pragma unroll
        for (int j = 0; j < 4; ++j) acc[i][j] = fmaf(a[i], bv[j], acc[i][j]);
    }
    __syncthreads();
  }
#pragma unroll
  for (int i = 0; i < 4; ++i) {
    int m = m0 + ty * 4 + i;
    if (m >= M) continue;
#pragma unroll
    for (int j = 0; j < 4; ++j) {
      int n = n0 + tx * 4 + j;
      if (n >= N) continue;
      C[(size_t)m * ldc + n] = acc[i][j] + (bias ? bias[n] : 0.f);
    }
  }
}

// ---------------- h0 = mean over L of enc ----------------
__global__ __launch_bounds__(256) void k_h0(const float* __restrict__ enc, float* __restrict__ h0) {
  int b = blockIdx.x;
  int j = blockIdx.y * 256 + threadIdx.x;
  float s = 0.f;
  for (int l = 0; l < NL; ++l) s += enc[((size_t)b * NL + l) * NH + j];
  h0[b * NH + j] = s / 49.0f;
}

// ---------------- inp0 = embed[start], seq[:,0,:] = inp0 ----------------
__global__ __launch_bounds__(256) void k_prep0(const float* __restrict__ embed,
    const int* __restrict__ start, float* __restrict__ inp0, float* __restrict__ seq) {
  int idx = blockIdx.x * 256 + threadIdx.x;
  int b = idx >> 9, j = idx & 511;
  float v = embed[(size_t)start[0] * NH + j];
  inp0[idx] = v;
  seq[((size_t)b * NT) * NH + j] = v;
}

// ============ M=64 x N=128 x K=128 GEMM tile (one block), partial-sum producer ============
// All 64 batches in one block => weight slice read ONCE for the whole batch.
__device__ __forceinline__ void gemm_64x128_k128(
    const float* __restrict__ A, int lda,    // A[64][k], pre-offset to k0
    const float* __restrict__ B, int ldb,    // B[k][c], pre-offset to (k0, c0)
    float* __restrict__ C, int ldc) {        // C[64][c], pre-offset to c0
  __shared__ float As[32][65];
  __shared__ float Bs[32][128];
  const int tid = threadIdx.x;
  const int tx = tid & 15, ty = tid >> 4;
  float acc[4][8] = {};
  for (int k0 = 0; k0 < 128; k0 += 32) {
#pragma unroll
    for (int q = 0; q < 2; ++q) {
      int flat = tid * 2 + q;                // 0..511
      int m = flat >> 3, kq = flat & 7;
      float4 v = *(const float4*)&A[(size_t)m * lda + k0 + kq * 4];
      As[kq * 4 + 0][m] = v.x; As[kq * 4 + 1][m] = v.y;
      As[kq * 4 + 2][m] = v.z; As[kq * 4 + 3][m] = v.w;
    }
#pragma unroll
    for (int i = 0; i < 4; ++i) {
      int flat = i * 256 + tid;              // 0..1023
      int kk = flat >> 5, c4 = flat & 31;
      *(float4*)&Bs[kk][c4 * 4] = *(const float4*)&B[(size_t)(k0 + kk) * ldb + c4 * 4];
    }
    __syncthreads();
#pragma unroll
    for (int kk = 0; kk < 32; ++kk) {
      float a[4], bv[8];
      *(float4*)a = *(const float4*)&As[kk][ty * 4];
      *(float4*)bv = *(const float4*)&Bs[kk][tx * 8];
      *(float4*)(bv + 4) = *(const float4*)&Bs[kk][tx * 8 + 4];
#pragma unroll
      for (int i = 0; i < 4; ++i)
#pragma unroll
        for (int j = 0; j < 8; ++j) acc[i][j] = fmaf(a[i], bv[j], acc[i][j]);
    }
    __syncthreads();
  }
#pragma unroll
  for (int i = 0; i < 4; ++i) {
    int m = ty * 4 + i;
    *(float4*)&C[(size_t)m * ldc + tx * 8] = *(float4*)&acc[i][0];
    *(float4*)&C[(size_t)m * ldc + tx * 8 + 4] = *(float4*)&acc[i][4];
  }
}

// ---- step kernel 1: partial slabs for att2 (cols 0..255) and hWc1 (cols 256..767) ----
// grid (6,4): nt = n-tile, s = k-split.  p1[s][64][768], NO bias (added by consumer).
__global__ __launch_bounds__(256) void k_p1(const float* __restrict__ h,
    const float* __restrict__ inp, const float* __restrict__ W_dec,
    const float* __restrict__ W_comb, float* __restrict__ p1) {
  const int nt = blockIdx.x, s = blockIdx.y;
  const float* A; const float* B; int ldb, outc0;
  if (nt < 2) { A = h + s * 128;   B = W_dec  + (size_t)(s * 128) * NA + nt * 128;       ldb = NA; outc0 = nt * 128; }
  else        { A = inp + s * 128; B = W_comb + (size_t)(s * 128) * NH + (nt - 2) * 128; ldb = NH; outc0 = 256 + (nt - 2) * 128; }
  float* C = p1 + ((size_t)s * 64) * 768 + outc0;
  gemm_64x128_k128(A, NH, B, ldb, C, 768);
}

// ---- step kernel 2 (per-batch): reduce p1, e, softmax, context, comb ----
__global__ __launch_bounds__(256) void k_s2(const float* __restrict__ att1,
    const float* __restrict__ p1, const float* __restrict__ encWc2,
    const float* __restrict__ b_dec, const float* __restrict__ b_comb,
    const float* __restrict__ W_full, const float* __restrict__ b_full,
    float* __restrict__ comb) {
  const int b = blockIdx.x;
  const int tid = threadIdx.x;
  const int lane = tid & 63, wave = tid >> 6;
  __shared__ float a2[NA];
  __shared__ float sE[64];
  {
    float v = b_dec[tid];
#pragma unroll
    for (int s = 0; s < 4; ++s) v += p1[((size_t)s * 64 + b) * 768 + tid];
    a2[tid] = v;
  }
  __syncthreads();
  for (int l = wave; l < NL; l += 4) {
    const float* row = att1 + ((size_t)b * NL + l) * NA;
    float s = 0.f;
    for (int a = lane; a < NA; a += 64)
      s = fmaf(W_full[a], tanhf(row[a] + a2[a]), s);
#pragma unroll
    for (int off = 32; off > 0; off >>= 1) s += __shfl_down(s, off);
    if (lane == 0) sE[l] = s + b_full[0];
  }
  __syncthreads();
  if (wave == 0) {
    float v = (lane < NL) ? sE[lane] : -INFINITY;
    float m = v;
#pragma unroll
    for (int off = 32; off > 0; off >>= 1) m = fmaxf(m, __shfl_xor(m, off));
    float e = (lane < NL) ? expf(v - m) : 0.f;
    float sum = e;
#pragma unroll
    for (int off = 32; off > 0; off >>= 1) sum += __shfl_xor(sum, off);
    if (lane < NL) sE[lane] = e / sum;
  }
  __syncthreads();
  for (int j = tid; j < NH; j += 256) {
    float acc = b_comb[j];
#pragma unroll
    for (int s = 0; s < 4; ++s) acc += p1[((size_t)s * 64 + b) * 768 + 256 + j];
    const float* ew = encWc2 + (size_t)b * NL * NH + j;
    for (int l = 0; l < NL; ++l) acc = fmaf(sE[l], ew[(size_t)l * NH], acc);
    comb[b * NH + j] = tanhf(acc);
  }
}

// ---- step kernel 3: gate partial slabs ----
// F (r|z fused over K=1024 concat[comb,h]): pF[8][64][1024]
// N: pN[4][64][1024]: cols 0..511 = comb@WihT_n, cols 512..1023 = h@WhhT_n
__global__ __launch_bounds__(256) void k_p3(const float* __restrict__ comb,
    const float* __restrict__ h, const float* __restrict__ WihT,
    const float* __restrict__ WhhT, float* __restrict__ pF, float* __restrict__ pN) {
  const int bid = blockIdx.x;
  const float* A; const float* B; float* C;
  if (bid < 64) {
    int nt = bid >> 3, s = bid & 7;
    int k0 = s * 128;
    if (k0 < 512) { A = comb + k0; B = WihT + (size_t)k0 * 1536 + nt * 128; }
    else          { A = h + (k0 - 512); B = WhhT + (size_t)(k0 - 512) * 1536 + nt * 128; }
    C = pF + ((size_t)s * 64) * 1024 + nt * 128;
  } else if (bid < 80) {
    int q = bid - 64, nt = q >> 2, s = q & 3;
    A = comb + s * 128;
    B = WihT + (size_t)(s * 128) * 1536 + 1024 + nt * 128;
    C = pN + ((size_t)s * 64) * 1024 + nt * 128;
  } else {
    int q = bid - 80, nt = q >> 2, s = q & 3;
    A = h + s * 128;
    B = WhhT + (size_t)(s * 128) * 1536 + 1024 + nt * 128;
    C = pN + ((size_t)s * 64) * 1024 + 512 + nt * 128;
  }
  gemm_64x128_k128(A, NH, B, 1536, C, 1024);
}

// ---- step kernel 4: reduce partials, GRU nonlinearity, h_new + seq write ----
__global__ __launch_bounds__(256) void k_p4(const float* __restrict__ pF,
    const float* __restrict__ pN, const float* __restrict__ b_ih,
    const float* __restrict__ b_hh, const float* __restrict__ hprev,
    float* __restrict__ hout, float* __restrict__ seq, int t) {
  const int b = blockIdx.x;
#pragma unroll
  for (int i = 0; i < 2; ++i) {
    int j = threadIdx.x + i * 256;
    float rp = b_ih[j] + b_hh[j];
    float zp = b_ih[NH + j] + b_hh[NH + j];
    float ni = b_ih[2 * NH + j];
    float nh = b_hh[2 * NH + j];
#pragma unroll
    for (int s = 0; s < 8; ++s) {
      const float* pf = pF + ((size_t)s * 64 + b) * 1024;
      rp += pf[j]; zp += pf[NH + j];
    }
#pragma unroll
    for (int s = 0; s < 4; ++s) {
      const float* pn = pN + ((size_t)s * 64 + b) * 1024;
      ni += pn[j]; nh += pn[NH + j];
    }
    float r = 1.f / (1.f + expf(-rp));
    float z = 1.f / (1.f + expf(-zp));
    float n = tanhf(ni + r * nh);
    float hv = (1.f - z) * n + z * hprev[b * NH + j];
    hout[b * NH + j] = hv;
    seq[((size_t)b * NT + t) * NH + j] = hv;
  }
}

// ---------------- projection + fused argmax ----------------
__global__ __launch_bounds__(256) void k_proj(const float* __restrict__ Wp,
    const float* __restrict__ seq, const float* __restrict__ bias,
    float* __restrict__ out, unsigned long long* __restrict__ packed) {
  __shared__ float As[32][128];
  __shared__ float Bs[32][81];
  const int tid = threadIdx.x;
  const int tx = tid & 15, ty = tid >> 4;
  const int v0 = blockIdx.x * 128;
  const int t0 = blockIdx.y * 80;
  const int b = blockIdx.z;
  float acc[8][5] = {};
  for (int k0 = 0; k0 < NH; k0 += 32) {
#pragma unroll
    for (int i = 0; i < 16; ++i) {
      int idx = i * 256 + tid;
      int kk = idx >> 7, v = idx & 127;
      int gv = v0 + v;
      As[kk][v] = (gv < NV) ? Wp[(size_t)(k0 + kk) * NV + gv] : 0.f;
    }
#pragma unroll
    for (int i = 0; i < 10; ++i) {
      int idx = i * 256 + tid;
      int t = idx >> 5, kk = idx & 31;
      int gt = t0 + t;
      Bs[kk][t] = (gt < NT) ? seq[((size_t)b * NT + gt) * NH + k0 + kk] : 0.f;
    }
    __syncthreads();
#pragma unroll
    for (int kk = 0; kk < 32; ++kk) {
      const float4 a0 = *(const float4*)&As[kk][ty * 8];
      const float4 a1 = *(const float4*)&As[kk][ty * 8 + 4];
      float av[8] = {a0.x, a0.y, a0.z, a0.w, a1.x, a1.y, a1.z, a1.w};
      float bv[5];
#pragma unroll
      for (int j = 0; j < 5; ++j) bv[j] = Bs[kk][tx * 5 + j];
#pragma unroll
      for (int i = 0; i < 8; ++i)
#pragma unroll
        for (int j = 0; j < 5; ++j) acc[i][j] = fmaf(av[i], bv[j], acc[i][j]);
    }
    __syncthreads();
  }
  float best[5] = {-INFINITY, -INFINITY, -INFINITY, -INFINITY, -INFINITY};
  int bestv[5] = {0, 0, 0, 0, 0};
#pragma unroll
  for (int i = 0; i < 8; ++i) {
    int gv = v0 + ty * 8 + i;
    if (gv >= NV) continue;
    float bi = bias[gv];
#pragma unroll
    for (int j = 0; j < 5; ++j) {
      int gt = t0 + tx * 5 + j;
      if (gt >= NT) continue;
      float val = acc[i][j] + bi;
      out[((size_t)b * NV + gv) * NT + gt] = val;
      if (val > best[j]) { best[j] = val; bestv[j] = gv; }
    }
  }
  __syncthreads();
  float* rb = &As[0][0];
  int* ri = (int*)&Bs[0][0];
#pragma unroll
  for (int j = 0; j < 5; ++j) {
    rb[ty * 80 + tx * 5 + j] = best[j];
    ri[ty * 80 + tx * 5 + j] = bestv[j];
  }
  __syncthreads();
  if (ty == 0) {
    for (int j = 0; j < 5; ++j) {
      int gt = t0 + tx * 5 + j;
      if (gt >= NT) continue;
      float bb = -INFINITY; int bv_ = 0;
      for (int g = 0; g < 16; ++g) {
        float v = rb[g * 80 + tx * 5 + j];
        if (v > bb) { bb = v; bv_ = ri[g * 80 + tx * 5 + j]; }
      }
      unsigned int u = __float_as_uint(bb);
      u = (u & 0x80000000u) ? ~u : (u | 0x80000000u);
      unsigned long long p = ((unsigned long long)u << 32) | (unsigned int)(NV - 1 - bv_);
      atomicMax(&packed[b * NT + gt], p);
    }
  }
}

__global__ __launch_bounds__(256) void k_tokens(const unsigned long long* __restrict__ packed,
    float* __restrict__ tok) {
  int i = blockIdx.x * 256 + threadIdx.x;
  if (i < NB * NT) {
    unsigned int low = (unsigned int)(packed[i] & 0xFFFFFFFFull);
    tok[i] = (float)(NV - 1 - (int)low);
  }
}

extern "C" void kernel_launch(void* const* d_in, const int* in_sizes, int n_in,
                              void* d_out, int out_size, void* d_ws, size_t ws_size,
                              hipStream_t stream) {
  const float* enc_feat = (const float*)d_in[0];
  const float* W_fp   = (const float*)d_in[1];
  const float* b_fp   = (const float*)d_in[2];
  const float* W_enc  = (const float*)d_in[3];
  const float* b_enc  = (const float*)d_in[4];
  const float* W_dec  = (const float*)d_in[5];
  const float* b_dec  = (const float*)d_in[6];
  const float* W_full = (const float*)d_in[7];
  const float* b_full = (const float*)d_in[8];
  const float* W_comb = (const float*)d_in[9];
  const float* b_comb = (const float*)d_in[10];
  const float* embed  = (const float*)d_in[11];
  const float* W_ih   = (const float*)d_in[12];
  const float* b_ih   = (const float*)d_in[13];
  const float* W_hh   = (const float*)d_in[14];
  const float* b_hh   = (const float*)d_in[15];
  const float* W_proj = (const float*)d_in[16];
  const float* b_proj = (const float*)d_in[17];
  const int*   start  = (const int*)d_in[18];

  float* wsf = (float*)d_ws;
  size_t o = 0;
  float* encT   = wsf + o; o += (size_t)NB * NL * NH;
  float* enc    = wsf + o; o += (size_t)NB * NL * NH;
  float* att1   = wsf + o; o += (size_t)NB * NL * NA;
  float* encWc2 = wsf + o; o += (size_t)NB * NL * NH;
  float* WihT   = wsf + o; o += (size_t)NH * 3 * NH;
  float* WhhT   = wsf + o; o += (size_t)NH * 3 * NH;
  float* seq    = wsf + o; o += (size_t)NB * NT * NH;
  float* hb0    = wsf + o; o += NB * NH;
  float* hb1    = wsf + o; o += NB * NH;
  float* inp0   = wsf + o; o += NB * NH;
  float* comb   = wsf + o; o += NB * NH;
  float* p1     = wsf + o; o += (size_t)4 * 64 * 768;
  float* pF     = wsf + o; o += (size_t)8 * 64 * 1024;
  float* pN     = wsf + o; o += (size_t)4 * 64 * 1024;
  unsigned long long* packed = (unsigned long long*)(wsf + o); o += 2 * NB * NT;

  // ---- precompute ----
  k_transpose<<<dim3(2, 16, 64), 256, 0, stream>>>(enc_feat, encT, NH, NL,
      (long long)NH * NL, (long long)NH * NL);
  k_gemm_bias<<<dim3(8, 49), 256, 0, stream>>>(encT, NH, W_fp, NH, enc, NH,
      NB * NL, NH, NH, b_fp);
  k_h0<<<dim3(64, 2), 256, 0, stream>>>(enc, hb0);
  k_prep0<<<128, 256, 0, stream>>>(embed, start, inp0, seq);
  k_transpose<<<dim3(16, 48, 1), 256, 0, stream>>>(W_ih, WihT, 3 * NH, NH, 0, 0);
  k_transpose<<<dim3(16, 48, 1), 256, 0, stream>>>(W_hh, WhhT, 3 * NH, NH, 0, 0);
  k_gemm_bias<<<dim3(4, 49), 256, 0, stream>>>(enc, NH, W_enc, NA, att1, NA,
      NB * NL, NA, NH, b_enc);
  k_gemm_bias<<<dim3(8, 49), 256, 0, stream>>>(enc, NH, W_comb + (size_t)NH * NH, NH,
      encWc2, NH, NB * NL, NH, NH, nullptr);

  // ---- sequential recurrence: 150 steps x 4 kernels, all GEMM-structured ----
  float* hprev = hb0;
  float* hnext = hb1;
  for (int t = 1; t < NT; ++t) {
    const float* inp = (t == 1) ? inp0 : hprev;
    k_p1<<<dim3(6, 4), 256, 0, stream>>>(hprev, inp, W_dec, W_comb, p1);
    k_s2<<<64, 256, 0, stream>>>(att1, p1, encWc2, b_dec, b_comb, W_full, b_full, comb);
    k_p3<<<96, 256, 0, stream>>>(comb, hprev, WihT, WhhT, pF, pN);
    k_p4<<<64, 256, 0, stream>>>(pF, pN, b_ih, b_hh, hprev, hnext, seq, t);
    float* tmp = hprev; hprev = hnext; hnext = tmp;
  }

  // ---- projection + argmax ----
  hipMemsetAsync(packed, 0, sizeof(unsigned long long) * NB * NT, stream);
  float* outf = (float*)d_out;
  k_proj<<<dim3(79, 2, 64), 256, 0, stream>>>(W_proj, seq, b_proj, outf, packed);
  k_tokens<<<38, 256, 0, stream>>>(packed, outf + (size_t)NB * NV * NT);
}